// Round 1
// baseline (218.613 us; speedup 1.0000x reference)
//
#include <hip/hip_runtime.h>

typedef float v2f __attribute__((ext_vector_type(2)));

#define DD   187   // input dim
#define HH   50    // hidden
#define PH   56    // padded hidden (2 groups of 28)
#define HPJ  28    // hidden per lane of pair
#define NP   14    // float2 pairs per lane
#define NC   5     // classes
#define RPB  128   // rows per block
#define BLK  256   // threads per block
#define DCH  64    // d-chunk
#define NCHUNK 3   // ceil(187/64)
#define BETA 0.9f

__device__ __forceinline__ float dpp_xor1(float v) {
    // quad_perm [1,0,3,2] -> exchange with lane^1
    return __builtin_bit_cast(float,
        __builtin_amdgcn_mov_dpp(__builtin_bit_cast(int, v), 0xB1, 0xF, 0xF, true));
}

__device__ __forceinline__ v2f spike2(v2f m) {
    // exact (m > 1) ? 1 : 0 per component:
    // fma(m, 2^60, -2^60) = round((m-1)*2^60); m>1 => >= 2^36 -> clamps to 1; m<=1 => <=0 -> 0
    const v2f BIG2  = { 0x1.0p60f,  0x1.0p60f};
    const v2f NBIG2 = {-0x1.0p60f, -0x1.0p60f};
    const v2f ONE2  = {1.f, 1.f};
    const v2f ZERO2 = {0.f, 0.f};
    v2f t = __builtin_elementwise_fma(m, BIG2, NBIG2);
    return __builtin_elementwise_min(__builtin_elementwise_max(t, ZERO2), ONE2);
}

__global__ __launch_bounds__(BLK, 1)
void snn_kernel(const float* __restrict__ x,
                const float* __restrict__ W1,
                const float* __restrict__ b1,
                const float* __restrict__ W2,
                const float* __restrict__ b2,
                const int*   __restrict__ nsp,
                float* __restrict__ out, int Brows)
{
    __shared__ float xs[RPB * 65];    // 33,280 B (row stride 65 -> conflict-free)
    __shared__ float w1t[DCH * PH];   // 14,336 B (d-major, h padded to 56)

    const int tid = threadIdx.x;
    const int p   = tid >> 1;         // row within block
    const int j   = tid & 1;          // half of hidden dim
    const int row = blockIdx.x * RPB + p;
    const int NS  = nsp[0];

    // ---------------- Phase 1: cur1 = x @ W1^T (chunked over d) ----------------
    v2f acc[NP];
#pragma unroll
    for (int i = 0; i < NP; ++i) acc[i] = (v2f){0.f, 0.f};

    for (int ch = 0; ch < NCHUNK; ++ch) {
        const int d0 = ch * DCH;
        // stage x chunk: lanes read 64 consecutive floats of one row (coalesced)
        for (int i = tid; i < RPB * DCH; i += BLK) {
            int r = i >> 6, dd = i & 63;
            int d = d0 + dd;
            xs[r * 65 + dd] = (d < DD) ? x[(size_t)(blockIdx.x * RPB + r) * DD + d] : 0.f;
        }
        // stage W1 transposed chunk: coalesced global read, scattered LDS write (once)
        for (int i = tid; i < DCH * PH; i += BLK) {
            int h = i >> 6, dd = i & 63;   // i = h*64 + dd
            int d = d0 + dd;
            w1t[dd * PH + h] = (h < HH && d < DD) ? W1[h * DD + d] : 0.f;
        }
        __syncthreads();

        const float* xr = xs + p * 65;
#pragma unroll 4
        for (int d = 0; d < DCH; ++d) {
            float xv = xr[d];
            const v2f* wr = (const v2f*)(w1t + d * PH + j * HPJ);  // 16B aligned
            v2f xvv = {xv, xv};
#pragma unroll
            for (int i = 0; i < NP; ++i)
                acc[i] = __builtin_elementwise_fma(xvv, wr[i], acc[i]);
        }
        __syncthreads();
    }

    // cur1 = acc + b1 (pads stay 0 -> padded neurons never spike)
    v2f c1[NP];
#pragma unroll
    for (int i = 0; i < NP; ++i) {
        int h0 = j * HPJ + 2 * i;
        v2f bb = { (h0     < HH) ? b1[h0]     : 0.f,
                   (h0 + 1 < HH) ? b1[h0 + 1] : 0.f };
        c1[i] = acc[i] + bb;
    }

    // W2 fragments and b2 into registers
    v2f w2r[NC][NP];
#pragma unroll
    for (int c = 0; c < NC; ++c)
#pragma unroll
        for (int i = 0; i < NP; ++i) {
            int h0 = j * HPJ + 2 * i;
            w2r[c][i] = { (h0     < HH) ? W2[c * HH + h0]     : 0.f,
                          (h0 + 1 < HH) ? W2[c * HH + h0 + 1] : 0.f };
        }
    float b2r[NC];
#pragma unroll
    for (int c = 0; c < NC; ++c) b2r[c] = b2[c];

    // ---------------- Phase 2: 100-step LIF recurrence ----------------
    v2f m1[NP], s1[NP];
#pragma unroll
    for (int i = 0; i < NP; ++i) { m1[i] = (v2f){0.f, 0.f}; s1[i] = (v2f){0.f, 0.f}; }
    float m2[NC];
#pragma unroll
    for (int c = 0; c < NC; ++c) m2[c] = 0.f;

    const size_t stepStride = (size_t)Brows * NC;
    // lane j=0 writes spk_rec, lane j=1 writes mem_rec
    float* optr = out + (size_t)row * NC + (j ? (size_t)NS * stepStride : 0);
    const v2f BETA2 = {BETA, BETA};

    for (int t = 0; t < NS; ++t) {
        v2f cp0 = {0.f,0.f}, cp1 = {0.f,0.f}, cp2 = {0.f,0.f}, cp3 = {0.f,0.f}, cp4 = {0.f,0.f};
#pragma unroll
        for (int i = 0; i < NP; ++i) {
            // mem1 = beta*mem1 + cur1 - reset1   (reset1 == spike of previous state)
            v2f m = __builtin_elementwise_fma(BETA2, m1[i], c1[i]) - s1[i];
            m1[i] = m;
            v2f s = spike2(m);   // spk1 this step (== reset1 next step)
            s1[i] = s;
            cp0 = __builtin_elementwise_fma(s, w2r[0][i], cp0);
            cp1 = __builtin_elementwise_fma(s, w2r[1][i], cp1);
            cp2 = __builtin_elementwise_fma(s, w2r[2][i], cp2);
            cp3 = __builtin_elementwise_fma(s, w2r[3][i], cp3);
            cp4 = __builtin_elementwise_fma(s, w2r[4][i], cp4);
        }
        // horizontal + cross-pair (DPP) reduction, then + b2
        float cur2[NC];
        cur2[0] = cp0.x + cp0.y; cur2[1] = cp1.x + cp1.y; cur2[2] = cp2.x + cp2.y;
        cur2[3] = cp3.x + cp3.y; cur2[4] = cp4.x + cp4.y;
#pragma unroll
        for (int c = 0; c < NC; ++c) {
            float v = cur2[c];
            v += dpp_xor1(v);
            cur2[c] = v + b2r[c];
        }
        // layer-2 LIF + record
#pragma unroll
        for (int c = 0; c < NC; ++c) {
            float mv = m2[c];
            float rp = (mv > 1.f) ? 1.f : 0.f;          // reset2 from previous mem2
            mv = fmaf(BETA, mv, cur2[c]) - rp;
            m2[c] = mv;
            float s2 = (mv > 1.f) ? 1.f : 0.f;          // spk2
            optr[c] = j ? mv : s2;
        }
        optr += stepStride;
    }
}

extern "C" void kernel_launch(void* const* d_in, const int* in_sizes, int n_in,
                              void* d_out, int out_size, void* d_ws, size_t ws_size,
                              hipStream_t stream) {
    const float* x  = (const float*)d_in[0];
    const float* W1 = (const float*)d_in[1];
    const float* b1 = (const float*)d_in[2];
    const float* W2 = (const float*)d_in[3];
    const float* b2 = (const float*)d_in[4];
    const int*   ns = (const int*)d_in[5];
    int B = in_sizes[0] / DD;          // 32768
    int nblocks = B / RPB;             // 256
    snn_kernel<<<nblocks, BLK, 0, stream>>>(x, W1, b1, W2, b2, ns, (float*)d_out, B);
}

// Round 2
// 215.918 us; speedup vs baseline: 1.0125x; 1.0125x over previous
//
#include <hip/hip_runtime.h>

typedef float v2f __attribute__((ext_vector_type(2)));

#define DD   187   // input dim
#define HH   50    // hidden
#define PH   56    // padded hidden (4 groups of 14)
#define HPJ  14    // hidden neurons per lane of quad
#define NP   7     // float2 pairs per lane
#define NC   5     // classes
#define RPB  64    // rows per block
#define BLK  256   // threads per block
#define DCH  64    // d-chunk
#define NCHUNK 3   // ceil(187/64)
#define BETA 0.9f

__device__ __forceinline__ float dpp_xor1(float v) {
    // quad_perm [1,0,3,2] -> exchange with lane^1
    return __builtin_bit_cast(float,
        __builtin_amdgcn_mov_dpp(__builtin_bit_cast(int, v), 0xB1, 0xF, 0xF, true));
}
__device__ __forceinline__ float dpp_xor2(float v) {
    // quad_perm [2,3,0,1] -> exchange with lane^2
    return __builtin_bit_cast(float,
        __builtin_amdgcn_mov_dpp(__builtin_bit_cast(int, v), 0x4E, 0xF, 0xF, true));
}

__device__ __forceinline__ float spike1(float m) {
    // exact (m > 1) ? 1 : 0 : fma(m,2^60,-2^60) >= 2^36 iff m>1 (f32), clamp to [0,1]
    float t = fmaf(m, 0x1.0p60f, -0x1.0p60f);
    return fminf(fmaxf(t, 0.f), 1.f);
}
__device__ __forceinline__ v2f spike2(v2f m) {
    const v2f BIG2  = { 0x1.0p60f,  0x1.0p60f};
    const v2f NBIG2 = {-0x1.0p60f, -0x1.0p60f};
    const v2f ONE2  = {1.f, 1.f};
    const v2f ZERO2 = {0.f, 0.f};
    v2f t = __builtin_elementwise_fma(m, BIG2, NBIG2);
    return __builtin_elementwise_min(__builtin_elementwise_max(t, ZERO2), ONE2);
}

__global__ __launch_bounds__(BLK, 2)
void snn_kernel(const float* __restrict__ x,
                const float* __restrict__ W1,
                const float* __restrict__ b1,
                const float* __restrict__ W2,
                const float* __restrict__ b2,
                const int*   __restrict__ nsp,
                float* __restrict__ out, int Brows)
{
    __shared__ float xs[RPB * 65];    // 16,640 B (row stride 65 -> conflict-free)
    __shared__ float w1t[DCH * PH];   // 14,336 B (d-major, h padded to 56)

    const int tid = threadIdx.x;
    const int p   = tid >> 2;         // row within block (quad id)
    const int k   = tid & 3;          // lane within quad: hidden slice + class owner
    const int row = blockIdx.x * RPB + p;
    const int NS  = nsp[0];

    // ---------------- Phase 1: cur1 = x @ W1^T (chunked over d) ----------------
    v2f acc[NP];
#pragma unroll
    for (int i = 0; i < NP; ++i) acc[i] = (v2f){0.f, 0.f};

    for (int ch = 0; ch < NCHUNK; ++ch) {
        const int d0 = ch * DCH;
        for (int i = tid; i < RPB * DCH; i += BLK) {
            int r = i >> 6, dd = i & 63;
            int d = d0 + dd;
            xs[r * 65 + dd] = (d < DD) ? x[(size_t)(blockIdx.x * RPB + r) * DD + d] : 0.f;
        }
        for (int i = tid; i < DCH * PH; i += BLK) {
            int h = i >> 6, dd = i & 63;   // i = h*64 + dd
            int d = d0 + dd;
            w1t[dd * PH + h] = (h < HH && d < DD) ? W1[h * DD + d] : 0.f;
        }
        __syncthreads();

        const float* xr = xs + p * 65;
#pragma unroll 4
        for (int d = 0; d < DCH; ++d) {
            float xv = xr[d];
            const v2f* wr = (const v2f*)(w1t + d * PH + k * HPJ);  // 8B aligned (14 even)
            v2f xvv = {xv, xv};
#pragma unroll
            for (int i = 0; i < NP; ++i)
                acc[i] = __builtin_elementwise_fma(xvv, wr[i], acc[i]);
        }
        __syncthreads();
    }

    // cur1 = acc + b1 (pads stay 0 -> padded neurons never spike)
    v2f c1[NP];
#pragma unroll
    for (int i = 0; i < NP; ++i) {
        int h0 = k * HPJ + 2 * i;
        v2f bb = { (h0     < HH) ? b1[h0]     : 0.f,
                   (h0 + 1 < HH) ? b1[h0 + 1] : 0.f };
        c1[i] = acc[i] + bb;
    }

    // W2 fragments (70 VGPRs) and per-lane b2 slices into registers
    v2f w2r[NC][NP];
#pragma unroll
    for (int c = 0; c < NC; ++c)
#pragma unroll
        for (int i = 0; i < NP; ++i) {
            int h0 = k * HPJ + 2 * i;
            w2r[c][i] = { (h0     < HH) ? W2[c * HH + h0]     : 0.f,
                          (h0 + 1 < HH) ? W2[c * HH + h0 + 1] : 0.f };
        }
    const float b2A = b2[k];   // lane k owns class k
    const float b2B = b2[4];   // lane 0 additionally owns class 4

    // ---------------- Phase 2: 100-step LIF recurrence ----------------
    v2f m1[NP], s1[NP];
#pragma unroll
    for (int i = 0; i < NP; ++i) { m1[i] = (v2f){0.f, 0.f}; s1[i] = (v2f){0.f, 0.f}; }
    float mA = 0.f, sA = 0.f, mB = 0.f, sB = 0.f;

    const size_t stride = (size_t)Brows * NC;
    float* spkBase = out;                          // + t*stride each step (wave-uniform)
    float* memBase = out + (size_t)NS * stride;
    const int offA = row * NC + k;                 // lanes k=0..3 -> 4 consecutive dwords
    const int offB = row * NC + 4;
    const v2f BETA2 = {BETA, BETA};

    for (int t = 0; t < NS; ++t) {
        v2f cp[NC];
#pragma unroll
        for (int c = 0; c < NC; ++c) cp[c] = (v2f){0.f, 0.f};
#pragma unroll
        for (int i = 0; i < NP; ++i) {
            // mem1 = beta*mem1 + cur1 - reset1 (reset1 == previous spike)
            v2f m = __builtin_elementwise_fma(BETA2, m1[i], c1[i]) - s1[i];
            m1[i] = m;
            v2f s = spike2(m);
            s1[i] = s;
#pragma unroll
            for (int c = 0; c < NC; ++c)
                cp[c] = __builtin_elementwise_fma(s, w2r[c][i], cp[c]);
        }
        // horizontal + quad butterfly reduction -> all 4 lanes have all 5 sums
        float cur2[NC];
#pragma unroll
        for (int c = 0; c < NC; ++c) {
            float r = cp[c].x + cp[c].y;
            r += dpp_xor1(r);
            r += dpp_xor2(r);
            cur2[c] = r;
        }
        // lane k owns class k (slot A); all lanes compute class 4 (slot B), lane 0 stores it
        float cA = (k == 0) ? cur2[0] : (k == 1) ? cur2[1] : (k == 2) ? cur2[2] : cur2[3];
        float cB = cur2[4];

        mA = fmaf(BETA, mA, cA + b2A) - sA;   // sA == (prev mA > 1) == reset
        sA = spike1(mA);
        mB = fmaf(BETA, mB, cB + b2B) - sB;
        sB = spike1(mB);

        spkBase[offA] = sA;                   // 4 consecutive dwords per quad
        memBase[offA] = mA;
        if (k == 0) { spkBase[offB] = sB; memBase[offB] = mB; }

        spkBase += stride;
        memBase += stride;
    }
}

extern "C" void kernel_launch(void* const* d_in, const int* in_sizes, int n_in,
                              void* d_out, int out_size, void* d_ws, size_t ws_size,
                              hipStream_t stream) {
    const float* x  = (const float*)d_in[0];
    const float* W1 = (const float*)d_in[1];
    const float* b1 = (const float*)d_in[2];
    const float* W2 = (const float*)d_in[3];
    const float* b2 = (const float*)d_in[4];
    const int*   ns = (const int*)d_in[5];
    int B = in_sizes[0] / DD;          // 32768
    int nblocks = B / RPB;             // 512 -> 2 blocks/CU, 8 waves/CU
    snn_kernel<<<nblocks, BLK, 0, stream>>>(x, W1, b1, W2, b2, ns, (float*)d_out, B);
}